// Round 3
// baseline (1988.482 us; speedup 1.0000x reference)
//
#include <hip/hip_runtime.h>
#include <hip/hip_bf16.h>
#include <stdint.h>

#define NBONDS 240000
#define NATOMS 120000
#define HID    256
#define ADIM   133
#define BDIM   14
#define MOLDIM 200
#define NMOL   4096
#define KI     160   // 147 padded
#define KM     256
#define KA     416   // 389 padded (K-order: [m_v(256) | atomf(133) | pad])
#define OUTW   456
#define BN_EPS 1e-5f
#define SLOPE  0.01f

typedef unsigned short u16;
typedef unsigned int   u32;
typedef __attribute__((ext_vector_type(8))) short short8;
typedef __attribute__((ext_vector_type(4))) float f32x4;

__device__ __forceinline__ float bf2f(u16 b){
  u32 u = ((u32)b) << 16;
  return __builtin_bit_cast(float, u);
}
__device__ __forceinline__ u16 f2bf(float f){
  u32 u = __builtin_bit_cast(u32, f);
  u32 r = (u + 0x7FFFu + ((u >> 16) & 1u)) >> 16;  // RNE
  return (u16)r;
}
__device__ __forceinline__ void gload16(const void* g, void* l){
  __builtin_amdgcn_global_load_lds((const __attribute__((address_space(1))) u32*)g,
                                   (__attribute__((address_space(3))) u32*)l, 16, 0, 0);
}
__device__ __forceinline__ float leaky(float v){ return v >= 0.f ? v : SLOPE*v; }

// ---------------- utility kernels ------------------------------------------
__global__ void zero_f(float* p, int n){
  int i = blockIdx.x*blockDim.x + threadIdx.x;
  if(i < n) p[i] = 0.f;
}
__global__ void diag_k(float* out, int n, float wsz){
  int i = blockIdx.x*blockDim.x + threadIdx.x;
  for(; i < n; i += gridDim.x*blockDim.x) out[i] = (i == 0) ? wsz : 0.f;
}

// wib [256][160] (pad 147->160); wmb [256][256]; wab [256][416] K-permuted:
// k<256 -> wa[:,133+k]; 256<=k<389 -> wa[:,k-256]; else 0
__global__ void cvt_weights(const float* wi, const float* wm, const float* wa,
                            u16* wib, u16* wmb, u16* wab){
  int idx = blockIdx.x*blockDim.x + threadIdx.x;
  const int T0 = 256*KI, T1 = T0 + 256*KM, T2 = T1 + 256*KA;
  for(; idx < T2; idx += gridDim.x*blockDim.x){
    if(idx < T0){
      int n = idx / KI, k = idx % KI;
      wib[idx] = f2bf(k < 147 ? wi[n*147+k] : 0.f);
    } else if(idx < T1){
      int j = idx - T0;
      wmb[j] = f2bf(wm[j]);
    } else {
      int j = idx - T1;
      int n = j / KA, k = j % KA;
      float v = 0.f;
      if(k < 256)      v = wa[n*389 + 133 + k];
      else if(k < 389) v = wa[n*389 + (k - 256)];
      wab[j] = f2bf(v);
    }
  }
}

__global__ void affine_k(const float* __restrict__ stats, float* __restrict__ aff,
                         float invN, const float* __restrict__ bnw, const float* __restrict__ bnb){
  int c = threadIdx.x;
  float mu  = stats[c] * invN;
  float var = stats[256+c]*invN - mu*mu;
  float rs  = rsqrtf(var + BN_EPS);
  float sc  = rs * bnw[c];
  aff[c]     = sc;
  aff[256+c] = bnb[c] - mu*sc;
}

// ============================================================================
// GEMM geometry (all 3 kernels): 256 thr = 4 waves (2M x 2N), BM=64, BN=256,
// BK=32, wave-tile 32x128, acc[2][8] f32x4. LDS chunk-planes [kc][row][8]:
// staging writes + frag reads both contiguous per quarter-wave (conflict-free).
// ============================================================================

// ---------------- stage 0: h0_pre = leaky(x0 @ Wi^T + bi) -------------------
__global__ __launch_bounds__(256) void gemm0_k(
    const float* __restrict__ bondf, const float* __restrict__ atomf,
    const int* __restrict__ bidx, const u16* __restrict__ wib,
    const float* __restrict__ bi_, u16* __restrict__ Hout,
    float* __restrict__ stats)
{
  __shared__ u16 lA[2][4][64][8];
  __shared__ u16 lB[2][4][256][8];
  __shared__ float sred[512];
  const int tid=threadIdx.x, wave=tid>>6, lane=tid&63;
  const int wm=wave>>1, wn=wave&1, l15=lane&15, l4=lane>>4;
  const int r=tid&63, c=tid>>6;
  const int row0=blockIdx.x*64, row=row0+r;
  const int src = bidx[row];

  f32x4 acc[2][8];
  #pragma unroll
  for(int i=0;i<2;i++)
    #pragma unroll
    for(int j=0;j<8;j++){ f32x4 z={0.f,0.f,0.f,0.f}; acc[i][j]=z; }

  auto stgB=[&](int buf,int ks){
    #pragma unroll
    for(int kc=0;kc<4;kc++)
      gload16(wib + (size_t)(wave*64+lane)*KI + ks*32 + kc*8, &lB[buf][kc][wave*64][0]);
  };
  auto stgA=[&](int buf,int ks){
    int k0 = ks*32 + c*8;
    short8 o;
    #pragma unroll
    for(int e=0;e<8;e++){
      int kg=k0+e; float x=0.f;
      if(kg<BDIM) x=bondf[row*BDIM+kg];
      else if(kg<BDIM+ADIM) x=atomf[(size_t)src*ADIM+kg-BDIM];
      o[e]=(short)f2bf(x);
    }
    *(short8*)&lA[buf][c][r][0]=o;
  };
  auto mm=[&](int cur){
    short8 af[2];
    #pragma unroll
    for(int mf=0;mf<2;mf++) af[mf]=*(const short8*)&lA[cur][l4][wm*32+mf*16+l15][0];
    #pragma unroll
    for(int nf=0;nf<8;nf++){
      short8 b8=*(const short8*)&lB[cur][l4][wn*128+nf*16+l15][0];
      #pragma unroll
      for(int mf=0;mf<2;mf++)
        acc[mf][nf]=__builtin_amdgcn_mfma_f32_16x16x32_bf16(af[mf],b8,acc[mf][nf],0,0,0);
    }
  };

  stgA(0,0); stgB(0,0);
  __syncthreads();
  #pragma unroll
  for(int ks=0;ks<5;ks++){
    int cur=ks&1;
    if(ks<4){ stgA(cur^1,ks+1); stgB(cur^1,ks+1); }
    mm(cur);
    __syncthreads();
  }
  sred[tid]=0.f; sred[256+tid]=0.f;
  __syncthreads();
  #pragma unroll
  for(int nf=0;nf<8;nf++){
    int col=wn*128+nf*16+l15;
    float bc=bi_[col], ps=0.f, pq=0.f;
    #pragma unroll
    for(int mf=0;mf<2;mf++)
      #pragma unroll
      for(int j=0;j<4;j++){
        int grow=row0+wm*32+mf*16+l4*4+j;
        float h=leaky(acc[mf][nf][j]+bc);
        Hout[(size_t)grow*HID+col]=f2bf(h);
        ps+=h; pq+=h*h;
      }
    atomicAdd(&sred[col],ps); atomicAdd(&sred[256+col],pq);
  }
  __syncthreads();
  atomicAdd(&stats[tid],sred[tid]); atomicAdd(&stats[256+tid],sred[256+tid]);
}

// ---------------- loop: h' = leaky(aff0(leaky(x0@Wi+bi)) + m@Wm + bm) -------
// m built in A-staging: sc_t*(sum_6 Hin[id] - Hin[rev]) + (cnt-1)*sh_t
__global__ __launch_bounds__(256) void gemml_k(
    const float* __restrict__ bondf, const float* __restrict__ atomf,
    const int* __restrict__ bidx, const int* __restrict__ brm,
    const int* __restrict__ aibm, const u16* __restrict__ Hin,
    const u16* __restrict__ zrow, const u16* __restrict__ wmb,
    const float* __restrict__ bm_, const u16* __restrict__ wib,
    const float* __restrict__ bi_, const float* __restrict__ ain,
    const float* __restrict__ aff0, u16* __restrict__ Hout,
    float* __restrict__ stats)
{
  __shared__ u16 lA[2][4][64][8];
  __shared__ u16 lB[2][4][256][8];
  __shared__ float sred[512];
  const int tid=threadIdx.x, wave=tid>>6, lane=tid&63;
  const int wm=wave>>1, wn=wave&1, l15=lane&15, l4=lane>>4;
  const int r=tid&63, c=tid>>6;
  const int row0=blockIdx.x*64, row=row0+r;

  // affine_t -> LDS (broadcast reads in staging)
  sred[tid]=ain[tid]; sred[256+tid]=ain[256+tid];

  const int src = bidx[row];
  const int rev = brm[row];
  const u16* gbase[7];
  int cnt=0;
  #pragma unroll
  for(int j=0;j<6;j++){
    int id = aibm[src*6+j];
    gbase[j] = (id>0) ? (Hin + (size_t)(id-1)*HID) : zrow;
    cnt += (id>0);
  }
  gbase[6] = Hin + (size_t)rev*HID;
  const float cntm1 = (float)(cnt-1);

  f32x4 acc[2][8];
  #pragma unroll
  for(int i=0;i<2;i++)
    #pragma unroll
    for(int j=0;j<8;j++){ f32x4 z={0.f,0.f,0.f,0.f}; acc[i][j]=z; }

  auto stgB=[&](int buf,int ks,const u16* W,int ldk){
    #pragma unroll
    for(int kc=0;kc<4;kc++)
      gload16(W + (size_t)(wave*64+lane)*ldk + ks*32 + kc*8, &lB[buf][kc][wave*64][0]);
  };
  auto stgA1=[&](int buf,int ks){
    int kofs = ks*32 + c*8;
    short8 v[7];
    #pragma unroll
    for(int j=0;j<7;j++) v[j]=*(const short8*)(gbase[j]+kofs);
    short8 o;
    #pragma unroll
    for(int e=0;e<8;e++){
      float s=0.f;
      #pragma unroll
      for(int j=0;j<6;j++) s+=bf2f((u16)v[j][e]);
      s-=bf2f((u16)v[6][e]);
      float mv = sred[kofs+e]*s + cntm1*sred[256+kofs+e];
      o[e]=(short)f2bf(mv);
    }
    *(short8*)&lA[buf][c][r][0]=o;
  };
  auto stgA0=[&](int buf,int ks){
    int k0 = ks*32 + c*8;
    short8 o;
    #pragma unroll
    for(int e=0;e<8;e++){
      int kg=k0+e; float x=0.f;
      if(kg<BDIM) x=bondf[row*BDIM+kg];
      else if(kg<BDIM+ADIM) x=atomf[(size_t)src*ADIM+kg-BDIM];
      o[e]=(short)f2bf(x);
    }
    *(short8*)&lA[buf][c][r][0]=o;
  };
  auto mm=[&](int cur){
    short8 af[2];
    #pragma unroll
    for(int mf=0;mf<2;mf++) af[mf]=*(const short8*)&lA[cur][l4][wm*32+mf*16+l15][0];
    #pragma unroll
    for(int nf=0;nf<8;nf++){
      short8 b8=*(const short8*)&lB[cur][l4][wn*128+nf*16+l15][0];
      #pragma unroll
      for(int mf=0;mf<2;mf++)
        acc[mf][nf]=__builtin_amdgcn_mfma_f32_16x16x32_bf16(af[mf],b8,acc[mf][nf],0,0,0);
    }
  };

  // ---- phase 1: acc = m @ Wm^T (K=256) ----
  __syncthreads();              // sred (affine) visible
  stgA1(0,0); stgB(0,0,wmb,KM);
  __syncthreads();
  #pragma unroll
  for(int ks=0;ks<8;ks++){
    int cur=ks&1;
    if(ks<7){ stgA1(cur^1,ks+1); stgB(cur^1,ks+1,wmb,KM); }
    mm(cur);
    __syncthreads();
  }
  // pack acc1 -> bf16
  u32 p1[2][8][2];
  #pragma unroll
  for(int mf=0;mf<2;mf++)
    #pragma unroll
    for(int nf=0;nf<8;nf++){
      p1[mf][nf][0]=((u32)f2bf(acc[mf][nf][1])<<16)|f2bf(acc[mf][nf][0]);
      p1[mf][nf][1]=((u32)f2bf(acc[mf][nf][3])<<16)|f2bf(acc[mf][nf][2]);
      f32x4 z={0.f,0.f,0.f,0.f}; acc[mf][nf]=z;
    }

  // ---- phase 2: acc = x0 @ Wi^T (K=160) ----
  stgA0(0,0); stgB(0,0,wib,KI);
  __syncthreads();
  #pragma unroll
  for(int ks=0;ks<5;ks++){
    int cur=ks&1;
    if(ks<4){ stgA0(cur^1,ks+1); stgB(cur^1,ks+1,wib,KI); }
    mm(cur);
    __syncthreads();
  }

  // ---- epilogue ----
  sred[tid]=0.f; sred[256+tid]=0.f;
  __syncthreads();
  #pragma unroll
  for(int nf=0;nf<8;nf++){
    int col=wn*128+nf*16+l15;
    float bic=bi_[col], bmc=bm_[col];
    float s0=aff0[col], t0=aff0[256+col];
    float ps=0.f,pq=0.f;
    #pragma unroll
    for(int mf=0;mf<2;mf++)
      #pragma unroll
      for(int j=0;j<4;j++){
        int grow=row0+wm*32+mf*16+l4*4+j;
        float v0 = leaky(acc[mf][nf][j]+bic);
        v0 = s0*v0 + t0;
        u32 pw = p1[mf][nf][j>>1];
        float u1 = bf2f((u16)((j&1) ? (pw>>16) : (pw&0xffff)));
        float h = leaky(v0 + u1 + bmc);
        Hout[(size_t)grow*HID+col]=f2bf(h);
        ps+=h; pq+=h*h;
      }
    atomicAdd(&sred[col],ps); atomicAdd(&sred[256+col],pq);
  }
  __syncthreads();
  atomicAdd(&stats[tid],sred[tid]); atomicAdd(&stats[256+tid],sred[256+tid]);
}

// ---------------- final: hv = leaky([m_v|atomf] @ Wa'^T + ba) ---------------
__global__ __launch_bounds__(256) void gemmf_k(
    const float* __restrict__ atomf, const int* __restrict__ aibm,
    const u16* __restrict__ Hin, const u16* __restrict__ zrow,
    const u16* __restrict__ wab, const float* __restrict__ ba_,
    const float* __restrict__ ain, u16* __restrict__ Hvout,
    float* __restrict__ stats)
{
  __shared__ u16 lA[2][4][64][8];
  __shared__ u16 lB[2][4][256][8];
  __shared__ float sred[512];
  const int tid=threadIdx.x, wave=tid>>6, lane=tid&63;
  const int wm=wave>>1, wn=wave&1, l15=lane&15, l4=lane>>4;
  const int r=tid&63, c=tid>>6;
  const int row0=blockIdx.x*64, row=row0+r;

  sred[tid]=ain[tid]; sred[256+tid]=ain[256+tid];

  const u16* gbase[6];
  int cnt=0;
  #pragma unroll
  for(int j=0;j<6;j++){
    int id = aibm[row*6+j];
    gbase[j] = (id>0) ? (Hin + (size_t)(id-1)*HID) : zrow;
    cnt += (id>0);
  }
  const float cntf = (float)cnt;

  f32x4 acc[2][8];
  #pragma unroll
  for(int i=0;i<2;i++)
    #pragma unroll
    for(int j=0;j<8;j++){ f32x4 z={0.f,0.f,0.f,0.f}; acc[i][j]=z; }

  auto stgB=[&](int buf,int ks){
    #pragma unroll
    for(int kc=0;kc<4;kc++)
      gload16(wab + (size_t)(wave*64+lane)*KA + ks*32 + kc*8, &lB[buf][kc][wave*64][0]);
  };
  auto stgA=[&](int buf,int ks){
    int k0 = ks*32 + c*8;
    short8 o;
    if(ks<8){
      short8 v[6];
      #pragma unroll
      for(int j=0;j<6;j++) v[j]=*(const short8*)(gbase[j]+k0);
      #pragma unroll
      for(int e=0;e<8;e++){
        float s=0.f;
        #pragma unroll
        for(int j=0;j<6;j++) s+=bf2f((u16)v[j][e]);
        float mv = sred[k0+e]*s + cntf*sred[256+k0+e];
        o[e]=(short)f2bf(mv);
      }
    } else {
      #pragma unroll
      for(int e=0;e<8;e++){
        int kg = k0 + e - 256;
        float x = (kg < ADIM) ? atomf[(size_t)row*ADIM + kg] : 0.f;
        o[e]=(short)f2bf(x);
      }
    }
    *(short8*)&lA[buf][c][r][0]=o;
  };
  auto mm=[&](int cur){
    short8 af[2];
    #pragma unroll
    for(int mf=0;mf<2;mf++) af[mf]=*(const short8*)&lA[cur][l4][wm*32+mf*16+l15][0];
    #pragma unroll
    for(int nf=0;nf<8;nf++){
      short8 b8=*(const short8*)&lB[cur][l4][wn*128+nf*16+l15][0];
      #pragma unroll
      for(int mf=0;mf<2;mf++)
        acc[mf][nf]=__builtin_amdgcn_mfma_f32_16x16x32_bf16(af[mf],b8,acc[mf][nf],0,0,0);
    }
  };

  __syncthreads();
  stgA(0,0); stgB(0,0);
  __syncthreads();
  #pragma unroll
  for(int ks=0;ks<13;ks++){
    int cur=ks&1;
    if(ks<12){ stgA(cur^1,ks+1); stgB(cur^1,ks+1); }
    mm(cur);
    __syncthreads();
  }
  sred[tid]=0.f; sred[256+tid]=0.f;
  __syncthreads();
  #pragma unroll
  for(int nf=0;nf<8;nf++){
    int col=wn*128+nf*16+l15;
    float bc=ba_[col], ps=0.f,pq=0.f;
    #pragma unroll
    for(int mf=0;mf<2;mf++)
      #pragma unroll
      for(int j=0;j<4;j++){
        int grow=row0+wm*32+mf*16+l4*4+j;
        float h=leaky(acc[mf][nf][j]+bc);
        Hvout[(size_t)grow*HID+col]=f2bf(h);
        ps+=h; pq+=h*h;
      }
    atomicAdd(&sred[col],ps); atomicAdd(&sred[256+col],pq);
  }
  __syncthreads();
  atomicAdd(&stats[tid],sred[tid]); atomicAdd(&stats[256+tid],sred[256+tid]);
}

// ---------------- molecule pooling + concat --------------------------------
__device__ __forceinline__ int lbound(const int* a, int n, int v){
  int lo = 0, hi = n;
  while(lo < hi){ int mid = (lo+hi) >> 1; if(a[mid] < v) lo = mid+1; else hi = mid; }
  return lo;
}

__global__ void pool_k(const u16* __restrict__ hv, const float* __restrict__ aff,
                       const int* __restrict__ a2m, const float* __restrict__ molf,
                       float* __restrict__ outp){
  int m = blockIdx.x;
  int t = threadIdx.x;
  int start = lbound(a2m, NATOMS, m);
  int end   = lbound(a2m, NATOMS, m+1);
  int rg = t >> 5, cg = t & 31;
  float s[8];
  #pragma unroll
  for(int j=0;j<8;j++) s[j] = 0.f;
  for(int a = start + rg; a < end; a += 8){
    short8 v = *(const short8*)(hv + (size_t)a*HID + cg*8);
    #pragma unroll
    for(int j=0;j<8;j++) s[j] += bf2f((u16)v[j]);
  }
  __shared__ float red[8][256];
  #pragma unroll
  for(int j=0;j<8;j++) red[rg][cg*8+j] = s[j];
  __syncthreads();
  if(t < 256){
    float S = 0.f;
    #pragma unroll
    for(int r=0;r<8;r++) S += red[r][t];
    float cnt = (float)(end - start);
    outp[(size_t)m*OUTW + t] = aff[t]*S + cnt*aff[256+t];
  }
  if(t < MOLDIM){
    outp[(size_t)m*OUTW + HID + t] = molf[(size_t)m*MOLDIM + t];
  }
}

// ---------------------------------------------------------------------------
extern "C" void kernel_launch(void* const* d_in, const int* in_sizes, int n_in,
                              void* d_out, int out_size, void* d_ws, size_t ws_size,
                              hipStream_t stream){
  const float* atomf = (const float*)d_in[0];
  const float* bondf = (const float*)d_in[1];
  const int*   bidx  = (const int*)  d_in[2];   // [2][NBONDS], row0 = src
  const float* molf  = (const float*)d_in[3];
  const int*   aibm  = (const int*)  d_in[4];
  const int*   brm   = (const int*)  d_in[5];
  const int*   a2m   = (const int*)  d_in[6];
  const float* wi    = (const float*)d_in[7];
  const float* bi    = (const float*)d_in[8];
  const float* wm    = (const float*)d_in[9];
  const float* bm    = (const float*)d_in[10];
  const float* wa    = (const float*)d_in[11];
  const float* ba    = (const float*)d_in[12];
  const float* bnw   = (const float*)d_in[13];
  const float* bnb   = (const float*)d_in[14];
  float* outp = (float*)d_out;

  // ---- workspace layout (~246.2 MB; ws_size = 256 MiB) ----
  char* wsp = (char*)d_ws;
  size_t off = 0;
  auto alloc = [&](size_t bytes)->void*{
    void* p = wsp + off; off += (bytes + 255) & ~(size_t)255; return p;
  };
  u16* HA   = (u16*)alloc((size_t)NBONDS*HID*2);   // 122.88 MB
  u16* HB   = (u16*)alloc((size_t)NBONDS*HID*2);   // 122.88 MB
  u16* wib  = (u16*)alloc((size_t)256*KI*2);
  u16* wmb  = (u16*)alloc((size_t)256*KM*2);
  u16* wab  = (u16*)alloc((size_t)256*KA*2);
  float* stats = (float*)alloc(5*512*sizeof(float));  // contiguous with affn+zrow
  float* affn  = (float*)alloc(5*512*sizeof(float));
  float* zrowf = (float*)alloc(512);
  size_t need = off;

  if(ws_size < need){
    diag_k<<<1024, 256, 0, stream>>>(outp, out_size, (float)ws_size);
    return;
  }
  const u16* zrow = (const u16*)zrowf;

  zero_f<<<(5248+255)/256, 256, 0, stream>>>(stats, 5248);  // stats+affn+zrow
  cvt_weights<<<416, 256, 0, stream>>>(wi, wm, wa, wib, wmb, wab);

  // stage 0 -> HA
  gemm0_k<<<NBONDS/64, 256, 0, stream>>>(bondf, atomf, bidx, wib, bi, HA, stats);
  affine_k<<<1, 256, 0, stream>>>(stats, affn, 1.f/NBONDS, bnw, bnb);

  // depth loop: HA->HB->HA->HB
  for(int t=0; t<3; t++){
    const u16* Hin  = (t & 1) ? HB : HA;
    u16*       Hout = (t & 1) ? HA : HB;
    gemml_k<<<NBONDS/64, 256, 0, stream>>>(bondf, atomf, bidx, brm, aibm,
                                           Hin, zrow, wmb, bm, wib, bi,
                                           affn + t*512, affn, Hout,
                                           stats + (t+1)*512);
    affine_k<<<1, 256, 0, stream>>>(stats + (t+1)*512, affn + (t+1)*512,
                                    1.f/NBONDS, bnw, bnb);
  }

  // final atom GEMM: gathers HB (h_3), writes hv -> HA (disjoint)
  gemmf_k<<<NATOMS/64, 256, 0, stream>>>(atomf, aibm, HB, zrow, wab, ba,
                                         affn + 3*512, HA, stats + 4*512);
  affine_k<<<1, 256, 0, stream>>>(stats + 4*512, affn + 4*512, 1.f/NATOMS, bnw, bnb);

  pool_k<<<NMOL, 256, 0, stream>>>(HA, affn + 4*512, a2m, molf, outp);
}

// Round 5
// 1870.383 us; speedup vs baseline: 1.0631x; 1.0631x over previous
//
#include <hip/hip_runtime.h>
#include <hip/hip_bf16.h>
#include <stdint.h>

#define NBONDS 240000
#define NATOMS 120000
#define HID    256
#define ADIM   133
#define BDIM   14
#define MOLDIM 200
#define NMOL   4096
#define KI     160   // 147 padded; K-order [atomf(133) | bondf(14) | pad]
#define KM     256
#define KA     416   // 389 padded; K-order [m_v(256) | atomf(133) | pad]
#define OUTW   456
#define BN_EPS 1e-5f
#define SLOPE  0.01f

typedef unsigned short u16;
typedef unsigned int   u32;
typedef __attribute__((ext_vector_type(8))) short short8;
typedef __attribute__((ext_vector_type(4))) float f32x4;

__device__ __forceinline__ float bf2f(u16 b){
  u32 u = ((u32)b) << 16;
  return __builtin_bit_cast(float, u);
}
__device__ __forceinline__ u16 f2bf(float f){
  u32 u = __builtin_bit_cast(u32, f);
  u32 r = (u + 0x7FFFu + ((u >> 16) & 1u)) >> 16;  // RNE
  return (u16)r;
}
__device__ __forceinline__ void gload16(const void* g, void* l){
  __builtin_amdgcn_global_load_lds((const __attribute__((address_space(1))) u32*)g,
                                   (__attribute__((address_space(3))) u32*)l, 16, 0, 0);
}
__device__ __forceinline__ float leaky(float v){ return v >= 0.f ? v : SLOPE*v; }

// ---------------- utility kernels ------------------------------------------
__global__ void zero_f(float* p, int n){
  int i = blockIdx.x*blockDim.x + threadIdx.x;
  if(i < n) p[i] = 0.f;
}
__global__ void diag_k(float* out, int n, float wsz){
  int i = blockIdx.x*blockDim.x + threadIdx.x;
  for(; i < n; i += gridDim.x*blockDim.x) out[i] = (i == 0) ? wsz : 0.f;
}

// wib [256][160]: k<133 -> wi[:,14+k] (atomf), 133<=k<147 -> wi[:,k-133] (bondf)
// wmb [256][256] plain; wab [256][416]: k<256 -> wa[:,133+k] (m_v), 256<=k<389 -> wa[:,k-256] (atomf)
__global__ void cvt_weights(const float* wi, const float* wm, const float* wa,
                            u16* wib, u16* wmb, u16* wab){
  int idx = blockIdx.x*blockDim.x + threadIdx.x;
  const int T0 = 256*KI, T1 = T0 + 256*KM, T2 = T1 + 256*KA;
  for(; idx < T2; idx += gridDim.x*blockDim.x){
    if(idx < T0){
      int n = idx / KI, k = idx % KI;
      float v = 0.f;
      if(k < 133)      v = wi[n*147 + 14 + k];
      else if(k < 147) v = wi[n*147 + (k - 133)];
      wib[idx] = f2bf(v);
    } else if(idx < T1){
      int j = idx - T0;
      wmb[j] = f2bf(wm[j]);
    } else {
      int j = idx - T1;
      int n = j / KA, k = j % KA;
      float v = 0.f;
      if(k < 256)      v = wa[n*389 + 133 + k];
      else if(k < 389) v = wa[n*389 + (k - 256)];
      wab[j] = f2bf(v);
    }
  }
}

__global__ void affine_k(const float* __restrict__ stats, float* __restrict__ aff,
                         float invN, const float* __restrict__ bnw, const float* __restrict__ bnb){
  int c = threadIdx.x;
  float mu  = stats[c] * invN;
  float var = stats[256+c]*invN - mu*mu;
  float rs  = rsqrtf(var + BN_EPS);
  float sc  = rs * bnw[c];
  aff[c]     = sc;
  aff[256+c] = bnb[c] - mu*sc;
}

// ---------------- per-bond message: m = sc*(sum6 - rev) + (cnt-1)*sh -------
// streaming, no LDS, high occupancy; 8 bonds/block, 32 lanes/bond (512B rows)
__global__ __launch_bounds__(256) void msg_k(
    const int* __restrict__ bidx, const int* __restrict__ brm,
    const int* __restrict__ aibm, const u16* __restrict__ Hin,
    const u16* __restrict__ zrow, const float* __restrict__ ain,
    u16* __restrict__ Mout)
{
  int t = threadIdx.x;
  int b = blockIdx.x*8 + (t>>5);
  int lane = t & 31;
  int src = bidx[b];
  int rev = brm[b];
  const u16* gb[7];
  int cnt = 0;
  #pragma unroll
  for(int j=0;j<6;j++){
    int id = aibm[src*6+j];
    gb[j] = (id>0) ? (Hin + (size_t)(id-1)*HID) : zrow;
    cnt += (id>0);
  }
  gb[6] = Hin + (size_t)rev*HID;
  int c = lane*8;
  short8 v[7];
  #pragma unroll
  for(int j=0;j<7;j++) v[j] = *(const short8*)(gb[j]+c);
  float cm1 = (float)(cnt-1);
  short8 o;
  #pragma unroll
  for(int e=0;e<8;e++){
    float s = 0.f;
    #pragma unroll
    for(int j=0;j<6;j++) s += bf2f((u16)v[j][e]);
    s -= bf2f((u16)v[6][e]);
    o[e] = (short)f2bf(ain[c+e]*s + cm1*ain[256+c+e]);
  }
  *(short8*)(Mout + (size_t)b*HID + c) = o;
}

// ---------------- per-atom m_v: sc*(sum6) + cnt*sh -------------------------
__global__ __launch_bounds__(256) void msgv_k(
    const int* __restrict__ aibm, const u16* __restrict__ Hin,
    const u16* __restrict__ zrow, const float* __restrict__ ain,
    u16* __restrict__ Mv)
{
  int t = threadIdx.x;
  int a = blockIdx.x*8 + (t>>5);
  int lane = t & 31;
  const u16* gb[6];
  int cnt = 0;
  #pragma unroll
  for(int j=0;j<6;j++){
    int id = aibm[a*6+j];
    gb[j] = (id>0) ? (Hin + (size_t)(id-1)*HID) : zrow;
    cnt += (id>0);
  }
  int c = lane*8;
  short8 v[6];
  #pragma unroll
  for(int j=0;j<6;j++) v[j] = *(const short8*)(gb[j]+c);
  float cf = (float)cnt;
  short8 o;
  #pragma unroll
  for(int e=0;e<8;e++){
    float s = 0.f;
    #pragma unroll
    for(int j=0;j<6;j++) s += bf2f((u16)v[j][e]);
    o[e] = (short)f2bf(ain[c+e]*s + cf*ain[256+c+e]);
  }
  *(short8*)(Mv + (size_t)a*HID + c) = o;
}

// ============================================================================
// GEMM geometry: 256 thr = 4 waves (2M x 2N), BM=64, BN=256, BK=32,
// wave-tile 32x128, acc[2][8] f32x4. LDS chunk-planes [kc][row][8].
// ============================================================================

// ---------------- stage 0: h0_pre = leaky(x0 @ Wi^T + bi) -------------------
__global__ __launch_bounds__(256) void gemm0_k(
    const float* __restrict__ bondf, const float* __restrict__ atomf,
    const int* __restrict__ bidx, const u16* __restrict__ wib,
    const float* __restrict__ bi_, u16* __restrict__ Hout,
    float* __restrict__ stats)
{
  __shared__ u16 lA[2][4][64][8];
  __shared__ u16 lB[2][4][256][8];
  __shared__ float sred[512];
  const int tid=threadIdx.x, wave=tid>>6, lane=tid&63;
  const int wm=wave>>1, wn=wave&1, l15=lane&15, l4=lane>>4;
  const int r=tid&63, c=tid>>6;
  const int row0=blockIdx.x*64, row=row0+r;
  const int src = bidx[row];

  f32x4 acc[2][8];
  #pragma unroll
  for(int i=0;i<2;i++)
    #pragma unroll
    for(int j=0;j<8;j++){ f32x4 z={0.f,0.f,0.f,0.f}; acc[i][j]=z; }

  auto stgB=[&](int buf,int ks){
    #pragma unroll
    for(int kc=0;kc<4;kc++)
      gload16(wib + (size_t)(wave*64+lane)*KI + ks*32 + kc*8, &lB[buf][kc][wave*64][0]);
  };
  auto stgA=[&](int buf,int ks){
    int k0 = ks*32 + c*8;
    short8 o;
    #pragma unroll
    for(int e=0;e<8;e++){
      int kg=k0+e; float x=0.f;
      if(kg<ADIM) x=atomf[(size_t)src*ADIM+kg];
      else if(kg<ADIM+BDIM) x=bondf[(size_t)row*BDIM+kg-ADIM];
      o[e]=(short)f2bf(x);
    }
    *(short8*)&lA[buf][c][r][0]=o;
  };
  auto mm=[&](int cur){
    short8 af[2];
    #pragma unroll
    for(int mf=0;mf<2;mf++) af[mf]=*(const short8*)&lA[cur][l4][wm*32+mf*16+l15][0];
    #pragma unroll
    for(int nf=0;nf<8;nf++){
      short8 b8=*(const short8*)&lB[cur][l4][wn*128+nf*16+l15][0];
      #pragma unroll
      for(int mf=0;mf<2;mf++)
        acc[mf][nf]=__builtin_amdgcn_mfma_f32_16x16x32_bf16(af[mf],b8,acc[mf][nf],0,0,0);
    }
  };

  stgA(0,0); stgB(0,0);
  __syncthreads();
  #pragma unroll
  for(int ks=0;ks<5;ks++){
    int cur=ks&1;
    if(ks<4){ stgA(cur^1,ks+1); stgB(cur^1,ks+1); }
    mm(cur);
    __syncthreads();
  }
  sred[tid]=0.f; sred[256+tid]=0.f;
  __syncthreads();
  #pragma unroll
  for(int nf=0;nf<8;nf++){
    int col=wn*128+nf*16+l15;
    float bc=bi_[col], ps=0.f, pq=0.f;
    #pragma unroll
    for(int mf=0;mf<2;mf++)
      #pragma unroll
      for(int j=0;j<4;j++){
        int grow=row0+wm*32+mf*16+l4*4+j;
        float h=leaky(acc[mf][nf][j]+bc);
        Hout[(size_t)grow*HID+col]=f2bf(h);
        ps+=h; pq+=h*h;
      }
    atomicAdd(&sred[col],ps); atomicAdd(&sred[256+col],pq);
  }
  __syncthreads();
  atomicAdd(&stats[tid],sred[tid]); atomicAdd(&stats[256+tid],sred[256+tid]);
}

// ---------------- loop: h' = leaky(aff0(leaky(x0@Wi+bi)) + m@Wm + bm) -------
// phase 1: dense A from Mh (in-place buffer); phase 2: x0 recompute.
__global__ __launch_bounds__(256) void gemml_k(
    const float* __restrict__ bondf, const float* __restrict__ atomf,
    const int* __restrict__ bidx, u16* __restrict__ Mh,
    const u16* __restrict__ wmb, const float* __restrict__ bm_,
    const u16* __restrict__ wib, const float* __restrict__ bi_,
    const float* __restrict__ aff0, float* __restrict__ stats)
{
  __shared__ u16 lA[2][4][64][8];
  __shared__ u16 lB[2][4][256][8];
  __shared__ float sred[512];
  const int tid=threadIdx.x, wave=tid>>6, lane=tid&63;
  const int wm=wave>>1, wn=wave&1, l15=lane&15, l4=lane>>4;
  const int r=tid&63, c=tid>>6;
  const int row0=blockIdx.x*64, row=row0+r;
  const int src = bidx[row];

  f32x4 acc[2][8];
  #pragma unroll
  for(int i=0;i<2;i++)
    #pragma unroll
    for(int j=0;j<8;j++){ f32x4 z={0.f,0.f,0.f,0.f}; acc[i][j]=z; }

  auto stgB=[&](int buf,int ks,const u16* W,int ldk){
    #pragma unroll
    for(int kc=0;kc<4;kc++)
      gload16(W + (size_t)(wave*64+lane)*ldk + ks*32 + kc*8, &lB[buf][kc][wave*64][0]);
  };
  auto stgA1=[&](int buf,int ks){   // dense: wave stages plane kc=wave
    gload16(Mh + (size_t)(row0+lane)*KM + ks*32 + wave*8, &lA[buf][wave][0][0]);
  };
  auto stgA0=[&](int buf,int ks){   // x0 recompute
    int k0 = ks*32 + c*8;
    short8 o;
    #pragma unroll
    for(int e=0;e<8;e++){
      int kg=k0+e; float x=0.f;
      if(kg<ADIM) x=atomf[(size_t)src*ADIM+kg];
      else if(kg<ADIM+BDIM) x=bondf[(size_t)row*BDIM+kg-ADIM];
      o[e]=(short)f2bf(x);
    }
    *(short8*)&lA[buf][c][r][0]=o;
  };
  auto mm=[&](int cur){
    short8 af[2];
    #pragma unroll
    for(int mf=0;mf<2;mf++) af[mf]=*(const short8*)&lA[cur][l4][wm*32+mf*16+l15][0];
    #pragma unroll
    for(int nf=0;nf<8;nf++){
      short8 b8=*(const short8*)&lB[cur][l4][wn*128+nf*16+l15][0];
      #pragma unroll
      for(int mf=0;mf<2;mf++)
        acc[mf][nf]=__builtin_amdgcn_mfma_f32_16x16x32_bf16(af[mf],b8,acc[mf][nf],0,0,0);
    }
  };

  // ---- phase 1: acc = m @ Wm^T (K=256, dense A) ----
  stgA1(0,0); stgB(0,0,wmb,KM);
  __syncthreads();
  #pragma unroll
  for(int ks=0;ks<8;ks++){
    int cur=ks&1;
    if(ks<7){ stgA1(cur^1,ks+1); stgB(cur^1,ks+1,wmb,KM); }
    mm(cur);
    __syncthreads();
  }
  // pack acc1 -> bf16
  u32 p1[2][8][2];
  #pragma unroll
  for(int mf=0;mf<2;mf++)
    #pragma unroll
    for(int nf=0;nf<8;nf++){
      p1[mf][nf][0]=((u32)f2bf(acc[mf][nf][1])<<16)|f2bf(acc[mf][nf][0]);
      p1[mf][nf][1]=((u32)f2bf(acc[mf][nf][3])<<16)|f2bf(acc[mf][nf][2]);
      f32x4 z={0.f,0.f,0.f,0.f}; acc[mf][nf]=z;
    }

  // ---- phase 2: acc = x0 @ Wi^T (K=160) ----
  stgA0(0,0); stgB(0,0,wib,KI);
  __syncthreads();
  #pragma unroll
  for(int ks=0;ks<5;ks++){
    int cur=ks&1;
    if(ks<4){ stgA0(cur^1,ks+1); stgB(cur^1,ks+1,wib,KI); }
    mm(cur);
    __syncthreads();
  }

  // ---- epilogue (in-place overwrite of Mh rows) ----
  sred[tid]=0.f; sred[256+tid]=0.f;
  __syncthreads();
  #pragma unroll
  for(int nf=0;nf<8;nf++){
    int col=wn*128+nf*16+l15;
    float bic=bi_[col], bmc=bm_[col];
    float s0=aff0[col], t0=aff0[256+col];
    float ps=0.f,pq=0.f;
    #pragma unroll
    for(int mf=0;mf<2;mf++)
      #pragma unroll
      for(int j=0;j<4;j++){
        int grow=row0+wm*32+mf*16+l4*4+j;
        float v0 = leaky(acc[mf][nf][j]+bic);
        v0 = s0*v0 + t0;
        u32 pw = p1[mf][nf][j>>1];
        float u1 = bf2f((u16)((j&1) ? (pw>>16) : (pw&0xffff)));
        float h = leaky(v0 + u1 + bmc);
        Mh[(size_t)grow*HID+col]=f2bf(h);
        ps+=h; pq+=h*h;
      }
    atomicAdd(&sred[col],ps); atomicAdd(&sred[256+col],pq);
  }
  __syncthreads();
  atomicAdd(&stats[tid],sred[tid]); atomicAdd(&stats[256+tid],sred[256+tid]);
}

// ---------------- final: hv = leaky([m_v|atomf] @ Wa'^T + ba), in-place -----
__global__ __launch_bounds__(256) void gemmf_k(
    const float* __restrict__ atomf, u16* __restrict__ Mv,
    const u16* __restrict__ wab, const float* __restrict__ ba_,
    float* __restrict__ stats)
{
  __shared__ u16 lA[2][4][64][8];
  __shared__ u16 lB[2][4][256][8];
  __shared__ float sred[512];
  const int tid=threadIdx.x, wave=tid>>6, lane=tid&63;
  const int wm=wave>>1, wn=wave&1, l15=lane&15, l4=lane>>4;
  const int r=tid&63, c=tid>>6;
  const int row0=blockIdx.x*64, row=row0+r;

  f32x4 acc[2][8];
  #pragma unroll
  for(int i=0;i<2;i++)
    #pragma unroll
    for(int j=0;j<8;j++){ f32x4 z={0.f,0.f,0.f,0.f}; acc[i][j]=z; }

  auto stgB=[&](int buf,int ks){
    #pragma unroll
    for(int kc=0;kc<4;kc++)
      gload16(wab + (size_t)(wave*64+lane)*KA + ks*32 + kc*8, &lB[buf][kc][wave*64][0]);
  };
  auto stgA=[&](int buf,int ks){
    if(ks<8){
      gload16(Mv + (size_t)(row0+lane)*KM + ks*32 + wave*8, &lA[buf][wave][0][0]);
    } else {
      int k0 = ks*32 + c*8 - 256;
      short8 o;
      #pragma unroll
      for(int e=0;e<8;e++){
        int kg = k0 + e;
        float x = (kg < ADIM) ? atomf[(size_t)row*ADIM + kg] : 0.f;
        o[e]=(short)f2bf(x);
      }
      *(short8*)&lA[buf][c][r][0]=o;
    }
  };
  auto mm=[&](int cur){
    short8 af[2];
    #pragma unroll
    for(int mf=0;mf<2;mf++) af[mf]=*(const short8*)&lA[cur][l4][wm*32+mf*16+l15][0];
    #pragma unroll
    for(int nf=0;nf<8;nf++){
      short8 b8=*(const short8*)&lB[cur][l4][wn*128+nf*16+l15][0];
      #pragma unroll
      for(int mf=0;mf<2;mf++)
        acc[mf][nf]=__builtin_amdgcn_mfma_f32_16x16x32_bf16(af[mf],b8,acc[mf][nf],0,0,0);
    }
  };

  stgA(0,0); stgB(0,0);
  __syncthreads();
  #pragma unroll
  for(int ks=0;ks<13;ks++){
    int cur=ks&1;
    if(ks<12){ stgA(cur^1,ks+1); stgB(cur^1,ks+1); }
    mm(cur);
    __syncthreads();
  }
  sred[tid]=0.f; sred[256+tid]=0.f;
  __syncthreads();
  #pragma unroll
  for(int nf=0;nf<8;nf++){
    int col=wn*128+nf*16+l15;
    float bc=ba_[col], ps=0.f,pq=0.f;
    #pragma unroll
    for(int mf=0;mf<2;mf++)
      #pragma unroll
      for(int j=0;j<4;j++){
        int grow=row0+wm*32+mf*16+l4*4+j;
        float h=leaky(acc[mf][nf][j]+bc);
        Mv[(size_t)grow*HID+col]=f2bf(h);
        ps+=h; pq+=h*h;
      }
    atomicAdd(&sred[col],ps); atomicAdd(&sred[256+col],pq);
  }
  __syncthreads();
  atomicAdd(&stats[tid],sred[tid]); atomicAdd(&stats[256+tid],sred[256+tid]);
}

// ---------------- molecule pooling + concat --------------------------------
__device__ __forceinline__ int lbound(const int* a, int n, int v){
  int lo = 0, hi = n;
  while(lo < hi){ int mid = (lo+hi) >> 1; if(a[mid] < v) lo = mid+1; else hi = mid; }
  return lo;
}

__global__ void pool_k(const u16* __restrict__ hv, const float* __restrict__ aff,
                       const int* __restrict__ a2m, const float* __restrict__ molf,
                       float* __restrict__ outp){
  int m = blockIdx.x;
  int t = threadIdx.x;
  int start = lbound(a2m, NATOMS, m);
  int end   = lbound(a2m, NATOMS, m+1);
  int rg = t >> 5, cg = t & 31;
  float s[8];
  #pragma unroll
  for(int j=0;j<8;j++) s[j] = 0.f;
  for(int a = start + rg; a < end; a += 8){
    short8 v = *(const short8*)(hv + (size_t)a*HID + cg*8);
    #pragma unroll
    for(int j=0;j<8;j++) s[j] += bf2f((u16)v[j]);
  }
  __shared__ float red[8][256];
  #pragma unroll
  for(int j=0;j<8;j++) red[rg][cg*8+j] = s[j];
  __syncthreads();
  if(t < 256){
    float S = 0.f;
    #pragma unroll
    for(int r=0;r<8;r++) S += red[r][t];
    float cnt = (float)(end - start);
    outp[(size_t)m*OUTW + t] = aff[t]*S + cnt*aff[256+t];
  }
  if(t < MOLDIM){
    outp[(size_t)m*OUTW + HID + t] = molf[(size_t)m*MOLDIM + t];
  }
}

// ---------------------------------------------------------------------------
extern "C" void kernel_launch(void* const* d_in, const int* in_sizes, int n_in,
                              void* d_out, int out_size, void* d_ws, size_t ws_size,
                              hipStream_t stream){
  const float* atomf = (const float*)d_in[0];
  const float* bondf = (const float*)d_in[1];
  const int*   bidx  = (const int*)  d_in[2];   // [2][NBONDS], row0 = src
  const float* molf  = (const float*)d_in[3];
  const int*   aibm  = (const int*)  d_in[4];
  const int*   brm   = (const int*)  d_in[5];
  const int*   a2m   = (const int*)  d_in[6];
  const float* wi    = (const float*)d_in[7];
  const float* bi    = (const float*)d_in[8];
  const float* wm    = (const float*)d_in[9];
  const float* bm    = (const float*)d_in[10];
  const float* wa    = (const float*)d_in[11];
  const float* ba    = (const float*)d_in[12];
  const float* bnw   = (const float*)d_in[13];
  const float* bnb   = (const float*)d_in[14];
  float* outp = (float*)d_out;

  // ---- workspace layout (~246.2 MB; ws_size = 256 MiB) ----
  char* wsp = (char*)d_ws;
  size_t off = 0;
  auto alloc = [&](size_t bytes)->void*{
    void* p = wsp + off; off += (bytes + 255) & ~(size_t)255; return p;
  };
  u16* HA   = (u16*)alloc((size_t)NBONDS*HID*2);   // 122.88 MB
  u16* HB   = (u16*)alloc((size_t)NBONDS*HID*2);   // 122.88 MB
  u16* wib  = (u16*)alloc((size_t)256*KI*2);
  u16* wmb  = (u16*)alloc((size_t)256*KM*2);
  u16* wab  = (u16*)alloc((size_t)256*KA*2);
  float* stats = (float*)alloc(5*512*sizeof(float));
  float* affn  = (float*)alloc(5*512*sizeof(float));
  float* zrowf = (float*)alloc(512);
  size_t need = off;

  if(ws_size < need){
    diag_k<<<1024, 256, 0, stream>>>(outp, out_size, (float)ws_size);
    return;
  }
  const u16* zrow = (const u16*)zrowf;

  zero_f<<<(5248+255)/256, 256, 0, stream>>>(stats, 5248);  // stats+affn+zrow
  cvt_weights<<<416, 256, 0, stream>>>(wi, wm, wa, wib, wmb, wab);

  // stage 0 -> HA (h0_pre)
  gemm0_k<<<NBONDS/64, 256, 0, stream>>>(bondf, atomf, bidx, wib, bi, HA, stats);
  affine_k<<<1, 256, 0, stream>>>(stats, affn, 1.f/NBONDS, bnw, bnb);

  // depth loop: msg (Hin -> Hout as m), gemm in-place on Hout
  // t=0: HA->HB; t=1: HB->HA; t=2: HA->HB  => h3_pre ends in HB
  for(int t=0; t<3; t++){
    const u16* Hin = (t & 1) ? HB : HA;
    u16*       Hm  = (t & 1) ? HA : HB;
    msg_k<<<NBONDS/8, 256, 0, stream>>>(bidx, brm, aibm, Hin, zrow,
                                        affn + t*512, Hm);
    gemml_k<<<NBONDS/64, 256, 0, stream>>>(bondf, atomf, bidx, Hm,
                                           wmb, bm, wib, bi, affn,
                                           stats + (t+1)*512);
    affine_k<<<1, 256, 0, stream>>>(stats + (t+1)*512, affn + (t+1)*512,
                                    1.f/NBONDS, bnw, bnb);
  }

  // final: m_v from HB (h3_pre) -> HA (first 61.4MB), atom GEMM in-place on HA
  msgv_k<<<NATOMS/8, 256, 0, stream>>>(aibm, HB, zrow, affn + 3*512, HA);
  gemmf_k<<<NATOMS/64, 256, 0, stream>>>(atomf, HA, wab, ba, stats + 4*512);
  affine_k<<<1, 256, 0, stream>>>(stats + 4*512, affn + 4*512, 1.f/NATOMS, bnw, bnb);

  pool_k<<<NMOL, 256, 0, stream>>>(HA, affn + 4*512, a2m, molf, outp);
}